// Round 7
// baseline (778.974 us; speedup 1.0000x reference)
//
#include <hip/hip_runtime.h>
#include <hip/hip_bf16.h>
#include <math.h>

// MultiLayerGRUParallel: B=32, S=4096, H=128, OUT=128, L=3
// r6 structure + NKS 512 -> 2048 (outmm was GRID-limited to 8 waves/CU; r4
// counters: 1.33 TB/s, MfmaUtil 0.8%, occ 33% -> latency-bound. r5's NKS=2048
// test was confounded by the scattered outred, now coalesced.)
// Pipeline (6 launches): prep0c -> kb(l0->l1) -> kb(l1->l2) -> scan3v2
//   -> outmm -> outred.  Carries from chunk totals (tot ping-pong).
#define B_   32
#define S_   4096
#define H_   128
#define OUT_ 128
#define P_   (B_*S_)       // 131072 positions
#define NC_  64            // time chunks per chain
#define CH_  (S_/NC_)      // 64 steps per chunk
#define NKS_ 2048          // split-K workgroups for final matmul (8 blk/CU)
#define KTOT_ (H_*S_)      // 524288
#define NEGINF_ (-__builtin_inff())
#define HTP_ 136           // hT row pitch (ushorts): 272B -> row bank rotates by 4
#define LOGHALF_ (-0.6931471805599453f)

typedef __bf16 bf16x8 __attribute__((ext_vector_type(8)));
typedef float  f32x4  __attribute__((ext_vector_type(4)));
typedef unsigned short ushort8_t __attribute__((ext_vector_type(8)));

// ---- fast math (|args| bounded <~10 in this net; tolerance 5.2e-2) ----
__device__ __forceinline__ float sp_(float x) {            // softplus
  return __logf(1.f + __expf(x));
}
__device__ __forceinline__ float logg_(float x) {          // _log_g
  float t = (x >= 0.f) ? (x + 0.5f) : __builtin_amdgcn_rcpf(1.f + __expf(-x));
  return __logf(t);
}
__device__ __forceinline__ float lae_(float a, float b) {  // logaddexp
  float m = fmaxf(a, b);
  float d = -fabsf(a - b);                 // lae(-inf,x)=x fine
  return m + __logf(1.f + __expf(d));
}
__device__ __forceinline__ float sigm_(float e) {          // sigmoid
  return __builtin_amdgcn_rcpf(1.f + __expf(-e));
}
__device__ __forceinline__ unsigned short f2bf_(float f) { // fp32->bf16 RNE
  unsigned int u = __float_as_uint(f);
  u += 0x7fffu + ((u >> 16) & 1u);
  return (unsigned short)(u >> 16);
}

// DPP inclusive add-scan over 64 lanes: 6 VALU ops, no LDS pipe.
#define DPPADD_(v, ctrl, rmask) \
  ((v) + __int_as_float(__builtin_amdgcn_update_dpp( \
      0, __float_as_int(v), (ctrl), (rmask), 0xf, true)))
__device__ __forceinline__ float wscan_(float v) {
  v = DPPADD_(v, 0x111, 0xf);  // row_shr:1
  v = DPPADD_(v, 0x112, 0xf);  // row_shr:2
  v = DPPADD_(v, 0x114, 0xf);  // row_shr:4
  v = DPPADD_(v, 0x118, 0xf);  // row_shr:8
  v = DPPADD_(v, 0x142, 0xa);  // row_bcast:15 -> rows 1,3
  v = DPPADD_(v, 0x143, 0xc);  // row_bcast:31 -> rows 2,3
  return v;
}

// ---------------- layer 0 prep + chunk totals (+ weight convert tail) -------
// blocks [0,2048): one chunk each; 256 thr = 4 waves; wave = one position/iter.
// blocks [2048,2176): convert [Wz;Wh] of layers 1,2 to bf16 256x128.
__global__ __launch_bounds__(256) void prep0c_kernel(
    const float* __restrict__ x,
    const float* __restrict__ Wz, const float* __restrict__ bz,
    const float* __restrict__ Wh, const float* __restrict__ bh,
    float* __restrict__ u, float* __restrict__ A, float* __restrict__ tot,
    const float* __restrict__ Wz1, const float* __restrict__ Wh1,
    const float* __restrict__ Wz2, const float* __restrict__ Wh2,
    unsigned short* __restrict__ Wc1, unsigned short* __restrict__ Wc2)
{
  __shared__ float tpart[4][128];
  if (blockIdx.x >= 2048) {            // weight-convert tail blocks
    int idx = (blockIdx.x - 2048) * 256 + threadIdx.x;  // < 32768
    Wc1[idx] = f2bf_(idx < 16384 ? Wz1[idx] : Wh1[idx - 16384]);
    Wc2[idx] = f2bf_(idx < 16384 ? Wz2[idx] : Wh2[idx - 16384]);
    return;
  }
  int lane = threadIdx.x & 63, w = threadIdx.x >> 6;
  float wz0 = Wz[lane], wz1 = Wz[lane + 64];
  float bz0 = bz[lane], bz1 = bz[lane + 64];
  float wh0 = Wh[lane], wh1 = Wh[lane + 64];
  float bh0 = bh[lane], bh1 = bh[lane + 64];
  int blk = blockIdx.x;                       // b*NC + c
  size_t base = (size_t)blk * (CH_ * H_);
  int pos0 = blk * CH_;
  float xv[16];
  #pragma unroll
  for (int j = 0; j < 16; ++j) xv[j] = x[pos0 + j * 4 + w];
  float t0 = NEGINF_, t1 = NEGINF_;
  #pragma unroll
  for (int j = 0; j < 16; ++j) {
    int i = j * 4 + w;
    float k0 = fmaf(xv[j], wz0, bz0), k1 = fmaf(xv[j], wz1, bz1);
    float g0 = fmaf(xv[j], wh0, bh0), g1 = fmaf(xv[j], wh1, bh1);
    float lc0 = -sp_(k0), lc1 = -sp_(k1);
    float lv0 = k0 + lc0 + logg_(g0);   // -sp(-k) == k - sp(k)
    float lv1 = k1 + lc1 + logg_(g1);
    float s0 = wscan_(lc0);
    float c0 = __shfl(s0, 63, 64);
    float s1 = wscan_(lc1) + c0;
    float u0 = lv0 - s0, u1 = lv1 - s1;
    size_t o = base + (size_t)i * H_;
    u[o + lane]      = u0;  u[o + 64 + lane] = u1;
    A[o + lane]      = s0;  A[o + 64 + lane] = s1;
    t0 = lae_(t0, u0); t1 = lae_(t1, u1);
  }
  tpart[w][lane] = t0; tpart[w][64 + lane] = t1;
  __syncthreads();
  if (w == 0) {
    int ch = lane;
    tot[(size_t)blk * H_ + ch] =
        lae_(lae_(tpart[0][ch], tpart[1][ch]), lae_(tpart[2][ch], tpart[3][ch]));
    ch = lane + 64;
    tot[(size_t)blk * H_ + ch] =
        lae_(lae_(tpart[0][ch], tpart[1][ch]), lae_(tpart[2][ch], tpart[3][ch]));
  }
}

// ---------------- fused: carry + scan3(layer l) + matmul xW(l+1) + epilogue -
// block = one chunk; 256 thr = 4 waves. h stays in LDS (bf16). u/A in-place.
// Phase-1 operands fully preloaded into registers (all loads in flight before
// the serial lae chain starts).
__global__ __launch_bounds__(256) void kb_kernel(
    const float* __restrict__ totIn,          // layer l chunk totals
    const unsigned short* __restrict__ Wc,    // layer l+1 [256][128] bf16
    const float* __restrict__ bz, const float* __restrict__ bh,
    float* __restrict__ u, float* __restrict__ A,  // in: layer l, out: layer l+1
    float* __restrict__ totOut)               // out: layer l+1 chunk totals
{
  __shared__ unsigned short hT[64][HTP_]; // 17.0 KB h of layer l (bf16), padded
  __shared__ union {
    float kg[16][260];                    // 16.25 KB one 16-row m-tile of [k|g]
    float scr[32][128];                   // 16 KB half1 local scans (phase 1)
  } ks;
  __shared__ float thand[128];            // half0 -> half1 carry handoff
  __shared__ float tpart[4][128];         // carry partials / per-wave tot partials
  int tid = threadIdx.x;
  int lane = tid & 63, w = tid >> 6;
  int l15 = lane & 15, quad = lane >> 4;
  int half = tid >> 7, ch = tid & 127;
  int blk = blockIdx.x;
  int cidx = blk & (NC_ - 1);             // chunk index within its chain
  size_t base = (size_t)blk * (CH_ * H_);

  // ---- carry preamble: reduce tot[chain, 0..cidx-1, ch] ----
  {
    const float* tp = totIn + (size_t)(blk - cidx) * H_ + ch;
    float p0 = NEGINF_, p1 = NEGINF_;
    int i = half;
    for (; i + 2 < cidx; i += 4) {
      float a0 = tp[(size_t)i * H_];
      float a1 = tp[(size_t)(i + 2) * H_];
      p0 = lae_(p0, a0); p1 = lae_(p1, a1);
    }
    for (; i < cidx; i += 2) p0 = lae_(p0, tp[(size_t)i * H_]);
    tpart[half * 2][ch] = p0; tpart[half * 2 + 1][ch] = p1;
  }
  __syncthreads();

  // ---- phase 1a ----
  if (half == 0) {
    float r = LOGHALF_;                     // t=0 init, then fold carry partials
    r = lae_(r, tpart[0][ch]); r = lae_(r, tpart[1][ch]);
    r = lae_(r, tpart[2][ch]); r = lae_(r, tpart[3][ch]);
    const float* up = u + base + ch;
    const float* Ap = A + base + ch;
    float uv[32], av[32];
    #pragma unroll
    for (int i = 0; i < 32; ++i) uv[i] = up[i * H_];
    #pragma unroll
    for (int i = 0; i < 32; ++i) av[i] = Ap[i * H_];
    #pragma unroll
    for (int i = 0; i < 32; ++i) {
      r = lae_(r, uv[i]);
      hT[i][ch] = f2bf_(sigm_(__expf(av[i] + r)));
    }
    thand[ch] = r;   // carry into position 32
  } else {
    float r = NEGINF_;
    const float* up = u + base + ch;
    float uv[32];
    #pragma unroll
    for (int i = 0; i < 32; ++i) uv[i] = up[(32 + i) * H_];
    #pragma unroll
    for (int i = 0; i < 32; ++i) { r = lae_(r, uv[i]); ks.scr[i][ch] = r; }
  }
  __syncthreads();
  // ---- phase 1b: half1 fixup with half0's carry ----
  if (half == 1) {
    float r31 = thand[ch];
    const float* Ap = A + base + ch;
    float av[32];
    #pragma unroll
    for (int i = 0; i < 32; ++i) av[i] = Ap[(32 + i) * H_];
    #pragma unroll
    for (int i = 0; i < 32; ++i) {
      float ri = lae_(r31, ks.scr[i][ch]);
      hT[32 + i][ch] = f2bf_(sigm_(__expf(av[i] + ri)));
    }
  }
  __syncthreads();

  float bz0v = bz[lane], bz1v = bz[lane + 64];
  float bh0v = bh[lane], bh1v = bh[lane + 64];
  float t0 = NEGINF_, t1 = NEGINF_;

  // ---- phase 2/3 per 16-row m-tile: MFMA then epilogue ----
  // wave w owns output cols [64w, 64w+64) of N=256 ([k|g]).
  for (int t = 0; t < 4; ++t) {
    f32x4 z = {0.f, 0.f, 0.f, 0.f};
    f32x4 acc[4] = {z, z, z, z};
    #pragma unroll
    for (int kk = 0; kk < 4; ++kk) {
      bf16x8 a = *reinterpret_cast<const bf16x8*>(&hT[t * 16 + l15][kk * 32 + quad * 8]);
      #pragma unroll
      for (int nt = 0; nt < 4; ++nt) {
        int n = w * 64 + nt * 16 + l15;
        bf16x8 bf = *reinterpret_cast<const bf16x8*>(Wc + n * 128 + kk * 32 + quad * 8);
        acc[nt] = __builtin_amdgcn_mfma_f32_16x16x32_bf16(a, bf, acc[nt], 0, 0, 0);
      }
    }
    __syncthreads();  // previous epilogue done reading kg (tile 0: scr dead)
    #pragma unroll
    for (int nt = 0; nt < 4; ++nt) {
      int col = w * 64 + nt * 16 + l15;
      #pragma unroll
      for (int r2 = 0; r2 < 4; ++r2)
        ks.kg[quad * 4 + r2][col] = acc[nt][r2];   // D: row=quad*4+r2, col=l15
    }
    __syncthreads();
    #pragma unroll
    for (int i = 0; i < 4; ++i) {
      int row = w + i * 4;            // wave-interleaved rows of the m-tile
      int sIdx = t * 16 + row;
      float k0 = ks.kg[row][lane]        + bz0v;
      float k1 = ks.kg[row][64 + lane]   + bz1v;
      float g0 = ks.kg[row][128 + lane]  + bh0v;
      float g1 = ks.kg[row][192 + lane]  + bh1v;
      float lc0 = -sp_(k0), lc1 = -sp_(k1);
      float lv0 = k0 + lc0 + logg_(g0);
      float lv1 = k1 + lc1 + logg_(g1);
      float s0 = wscan_(lc0);
      float c0 = __shfl(s0, 63, 64);
      float s1 = wscan_(lc1) + c0;
      float u0 = lv0 - s0, u1 = lv1 - s1;
      size_t o = base + (size_t)sIdx * H_;
      u[o + lane]      = u0;  u[o + 64 + lane] = u1;
      A[o + lane]      = s0;  A[o + 64 + lane] = s1;
      t0 = lae_(t0, u0); t1 = lae_(t1, u1);
    }
  }

  // ---- combine chunk totals across the 4 waves ----
  tpart[w][lane] = t0; tpart[w][64 + lane] = t1;
  __syncthreads();
  if (w == 0) {
    int c = lane;
    totOut[(size_t)blk * H_ + c] =
        lae_(lae_(tpart[0][c], tpart[1][c]), lae_(tpart[2][c], tpart[3][c]));
    c = lane + 64;
    totOut[(size_t)blk * H_ + c] =
        lae_(lae_(tpart[0][c], tpart[1][c]), lae_(tpart[2][c], tpart[3][c]));
  }
}

// ---------------- layer 2 final scan -> hbf (bf16), split-chain + carry -----
__global__ __launch_bounds__(256) void scan3v2_kernel(
    const float* __restrict__ u, const float* __restrict__ A,
    const float* __restrict__ totIn, unsigned short* __restrict__ hbf)
{
  __shared__ float scr[32][128];
  __shared__ float thand[128];
  __shared__ float tpart[4][128];
  int tid = threadIdx.x;
  int half = tid >> 7, ch = tid & 127;
  int blk = blockIdx.x;
  int cidx = blk & (NC_ - 1);
  size_t base = (size_t)blk * (CH_ * H_);
  const float* up = u + base + ch;
  const float* Ap = A + base + ch;
  unsigned short* hp = hbf + base + ch;

  // ---- carry preamble ----
  {
    const float* tp = totIn + (size_t)(blk - cidx) * H_ + ch;
    float p0 = NEGINF_, p1 = NEGINF_;
    int i = half;
    for (; i + 2 < cidx; i += 4) {
      float a0 = tp[(size_t)i * H_];
      float a1 = tp[(size_t)(i + 2) * H_];
      p0 = lae_(p0, a0); p1 = lae_(p1, a1);
    }
    for (; i < cidx; i += 2) p0 = lae_(p0, tp[(size_t)i * H_]);
    tpart[half * 2][ch] = p0; tpart[half * 2 + 1][ch] = p1;
  }
  __syncthreads();

  if (half == 0) {
    float r = LOGHALF_;
    r = lae_(r, tpart[0][ch]); r = lae_(r, tpart[1][ch]);
    r = lae_(r, tpart[2][ch]); r = lae_(r, tpart[3][ch]);
    float uv[32], av[32];
    #pragma unroll
    for (int i = 0; i < 32; ++i) uv[i] = up[i * H_];
    #pragma unroll
    for (int i = 0; i < 32; ++i) av[i] = Ap[i * H_];
    #pragma unroll
    for (int i = 0; i < 32; ++i) {
      r = lae_(r, uv[i]);
      hp[(size_t)i * H_] = f2bf_(sigm_(__expf(av[i] + r)));
    }
    thand[ch] = r;
  } else {
    float r = NEGINF_;
    float uv[32];
    #pragma unroll
    for (int i = 0; i < 32; ++i) uv[i] = up[(32 + i) * H_];
    #pragma unroll
    for (int i = 0; i < 32; ++i) { r = lae_(r, uv[i]); scr[i][ch] = r; }
  }
  __syncthreads();
  if (half == 1) {
    float r31 = thand[ch];
    float av[32];
    #pragma unroll
    for (int i = 0; i < 32; ++i) av[i] = Ap[(32 + i) * H_];
    #pragma unroll
    for (int i = 0; i < 32; ++i) {
      float ri = lae_(r31, scr[i][ch]);
      hp[(size_t)(32 + i) * H_] = f2bf_(sigm_(__expf(av[i] + ri)));
    }
  }
}

// ---------------- final matmul: out[32,128] = h2flat @ Wout^T + bout --------
// NKS=2048 -> KSL=256, 8 blocks/CU (32 waves/CU) for latency hiding; plus
// 2-stage register pipeline.
__device__ __forceinline__ void omload_(
    const unsigned short* ap0, const unsigned short* ap1,
    const float* wp0, const float* wp1, int k,
    bf16x8& a0r, bf16x8& a1r, float4 (&wr)[2][2])
{
  a0r = *reinterpret_cast<const bf16x8*>(ap0 + k);
  a1r = *reinterpret_cast<const bf16x8*>(ap1 + k);
  wr[0][0] = *reinterpret_cast<const float4*>(wp0 + k);
  wr[0][1] = *reinterpret_cast<const float4*>(wp0 + k + 4);
  wr[1][0] = *reinterpret_cast<const float4*>(wp1 + k);
  wr[1][1] = *reinterpret_cast<const float4*>(wp1 + k + 4);
}
__device__ __forceinline__ void omstep_(
    const bf16x8& a0r, const bf16x8& a1r,
    const float4 (&wr)[2][2], f32x4 (&acc)[2][2])
{
  #pragma unroll
  for (int nt = 0; nt < 2; ++nt) {
    ushort8_t tt;
    tt[0] = f2bf_(wr[nt][0].x); tt[1] = f2bf_(wr[nt][0].y);
    tt[2] = f2bf_(wr[nt][0].z); tt[3] = f2bf_(wr[nt][0].w);
    tt[4] = f2bf_(wr[nt][1].x); tt[5] = f2bf_(wr[nt][1].y);
    tt[6] = f2bf_(wr[nt][1].z); tt[7] = f2bf_(wr[nt][1].w);
    bf16x8 bf = __builtin_bit_cast(bf16x8, tt);
    acc[0][nt] = __builtin_amdgcn_mfma_f32_16x16x32_bf16(a0r, bf, acc[0][nt], 0, 0, 0);
    acc[1][nt] = __builtin_amdgcn_mfma_f32_16x16x32_bf16(a1r, bf, acc[1][nt], 0, 0, 0);
  }
}

__global__ __launch_bounds__(256) void outmm_kernel(
    const unsigned short* __restrict__ hbf,  // 32 x 524288 bf16
    const float* __restrict__ Wout,          // 128 x 524288 fp32
    float* __restrict__ part)
{
  const int KSL = KTOT_ / NKS_;  // 256
  int tid = threadIdx.x, w = tid >> 6, lane = tid & 63;
  int l15 = lane & 15, quad = lane >> 4;
  int k0base = blockIdx.x * KSL;
  const unsigned short* ap0 = hbf + (size_t)l15 * KTOT_ + k0base + quad * 8;
  const unsigned short* ap1 = hbf + (size_t)(16 + l15) * KTOT_ + k0base + quad * 8;
  const float* wp0 = Wout + (size_t)(w * 32 + l15) * KTOT_ + k0base + quad * 8;
  const float* wp1 = Wout + (size_t)(w * 32 + 16 + l15) * KTOT_ + k0base + quad * 8;
  f32x4 acc[2][2] = {{{0,0,0,0},{0,0,0,0}},{{0,0,0,0},{0,0,0,0}}};
  bf16x8 aA0, aA1, aB0, aB1;
  float4 wvA[2][2], wvB[2][2];
  omload_(ap0, ap1, wp0, wp1, 0, aA0, aA1, wvA);
  for (int ks = 0; ks < KSL; ks += 64) {
    omload_(ap0, ap1, wp0, wp1, ks + 32, aB0, aB1, wvB);
    omstep_(aA0, aA1, wvA, acc);
    if (ks + 64 < KSL) omload_(ap0, ap1, wp0, wp1, ks + 64, aA0, aA1, wvA);
    omstep_(aB0, aB1, wvB, acc);
  }
  float* pp = part + (size_t)blockIdx.x * (B_ * OUT_);
  #pragma unroll
  for (int mt = 0; mt < 2; ++mt)
    #pragma unroll
    for (int nt = 0; nt < 2; ++nt)
      #pragma unroll
      for (int r = 0; r < 4; ++r) {
        int b = mt * 16 + quad * 4 + r;
        int o = w * 32 + nt * 16 + l15;
        pp[b * OUT_ + o] = acc[mt][nt][r];
      }
}

// ---------------- coalesced split-K reduction ------------------------------
// 64 blocks x 64 outputs. Lane reads part[wg][idx0+lane]: contiguous 256B per
// wave-instruction.
__global__ __launch_bounds__(256) void outred_kernel(
    const float* __restrict__ part, const float* __restrict__ bout,
    float* __restrict__ out)
{
  __shared__ float red[4][64];
  int w = threadIdx.x >> 6, lane = threadIdx.x & 63;
  int idx0 = blockIdx.x * 64;
  float s = 0.f;
  for (int wg = w; wg < NKS_; wg += 4)
    s += part[(size_t)wg * (B_ * OUT_) + idx0 + lane];
  red[w][lane] = s;
  __syncthreads();
  if (w == 0) {
    float r = (red[0][lane] + red[1][lane]) + (red[2][lane] + red[3][lane]);
    int idx = idx0 + lane;
    out[idx] = r + bout[idx & (OUT_ - 1)];
  }
}

// ---------------- host launcher ----------------
extern "C" void kernel_launch(void* const* d_in, const int* in_sizes, int n_in,
                              void* d_out, int out_size, void* d_ws, size_t ws_size,
                              hipStream_t stream)
{
  const float* x    = (const float*)d_in[0];
  const float* Wz[3] = {(const float*)d_in[1], (const float*)d_in[5], (const float*)d_in[9]};
  const float* bz[3] = {(const float*)d_in[2], (const float*)d_in[6], (const float*)d_in[10]};
  const float* Wh[3] = {(const float*)d_in[3], (const float*)d_in[7], (const float*)d_in[11]};
  const float* bh[3] = {(const float*)d_in[4], (const float*)d_in[8], (const float*)d_in[12]};
  const float* Wout = (const float*)d_in[13];
  const float* bout = (const float*)d_in[14];
  float* out = (float*)d_out;

  char* ws = (char*)d_ws;
  float*          u     = (float*)(ws + 0);                  // 64 MiB
  float*          A     = (float*)(ws + 67108864);           // 64 MiB
  unsigned short* hbf   = (unsigned short*)(ws + 134217728); // 32 MiB
  unsigned short* Wc1   = (unsigned short*)(ws + 167772160); // 64 KiB
  unsigned short* Wc2   = (unsigned short*)(ws + 167837696); // 64 KiB
  float*          totA  = (float*)(ws + 167903232);          // 1 MiB
  float*          totB  = (float*)(ws + 168951808);          // 1 MiB
  float*          part  = (float*)(ws + 170000384);          // 32 MiB

  // layer 0 prep + totals (+ weight convert in tail blocks)
  prep0c_kernel<<<B_ * NC_ + 128, 256, 0, stream>>>(
      x, Wz[0], bz[0], Wh[0], bh[0], u, A, totA,
      Wz[1], Wh[1], Wz[2], Wh[2], Wc1, Wc2);

  // layer 0 -> 1 fused, layer 1 -> 2 fused (tot ping-pongs A->B->A)
  kb_kernel<<<B_ * NC_, 256, 0, stream>>>(totA, Wc1, bz[1], bh[1], u, A, totB);
  kb_kernel<<<B_ * NC_, 256, 0, stream>>>(totB, Wc2, bz[2], bh[2], u, A, totA);

  // layer 2 final scan -> hbf
  scan3v2_kernel<<<B_ * NC_, 256, 0, stream>>>(u, A, totA, hbf);

  // output head
  outmm_kernel<<<NKS_, 256, 0, stream>>>(hbf, Wout, part);
  outred_kernel<<<(B_ * OUT_) / 64, 256, 0, stream>>>(part, bout, out);
}

// Round 8
// 670.913 us; speedup vs baseline: 1.1611x; 1.1611x over previous
//
#include <hip/hip_runtime.h>
#include <hip/hip_bf16.h>
#include <math.h>

// MultiLayerGRUParallel: B=32, S=4096, H=128, OUT=128, L=3
// r6 structure (NKS=512; NKS=2048 regressed twice: r5 +19us, r7 +117us) with
// ONE change: u/A stored INTERLEAVED as float2 {u, A} -> half the memory
// instructions in every scan-class kernel (loads 64->32, stores 4->2 per
// thread), same bytes, 512B per wave-instruction. Attacks the measured
// ~1.3 TB/s effective-BW / latency-bound regime (r4 counters).
// Pipeline (6 launches): prep0c -> kb(l0->l1) -> kb(l1->l2) -> scan3v2
//   -> outmm -> outred.  Carries from chunk totals (tot ping-pong).
#define B_   32
#define S_   4096
#define H_   128
#define OUT_ 128
#define P_   (B_*S_)       // 131072 positions
#define NC_  64            // time chunks per chain
#define CH_  (S_/NC_)      // 64 steps per chunk
#define NKS_ 512           // split-K workgroups for final matmul
#define KTOT_ (H_*S_)      // 524288
#define NEGINF_ (-__builtin_inff())
#define HTP_ 136           // hT row pitch (ushorts): 272B -> row bank rotates by 4
#define LOGHALF_ (-0.6931471805599453f)

typedef __bf16 bf16x8 __attribute__((ext_vector_type(8)));
typedef float  f32x4  __attribute__((ext_vector_type(4)));
typedef unsigned short ushort8_t __attribute__((ext_vector_type(8)));

// ---- fast math (|args| bounded <~10 in this net; tolerance 5.2e-2) ----
__device__ __forceinline__ float sp_(float x) {            // softplus
  return __logf(1.f + __expf(x));
}
__device__ __forceinline__ float logg_(float x) {          // _log_g
  float t = (x >= 0.f) ? (x + 0.5f) : __builtin_amdgcn_rcpf(1.f + __expf(-x));
  return __logf(t);
}
__device__ __forceinline__ float lae_(float a, float b) {  // logaddexp
  float m = fmaxf(a, b);
  float d = -fabsf(a - b);                 // lae(-inf,x)=x fine
  return m + __logf(1.f + __expf(d));
}
__device__ __forceinline__ float sigm_(float e) {          // sigmoid
  return __builtin_amdgcn_rcpf(1.f + __expf(-e));
}
__device__ __forceinline__ unsigned short f2bf_(float f) { // fp32->bf16 RNE
  unsigned int u = __float_as_uint(f);
  u += 0x7fffu + ((u >> 16) & 1u);
  return (unsigned short)(u >> 16);
}

// DPP inclusive add-scan over 64 lanes: 6 VALU ops, no LDS pipe.
#define DPPADD_(v, ctrl, rmask) \
  ((v) + __int_as_float(__builtin_amdgcn_update_dpp( \
      0, __float_as_int(v), (ctrl), (rmask), 0xf, true)))
__device__ __forceinline__ float wscan_(float v) {
  v = DPPADD_(v, 0x111, 0xf);  // row_shr:1
  v = DPPADD_(v, 0x112, 0xf);  // row_shr:2
  v = DPPADD_(v, 0x114, 0xf);  // row_shr:4
  v = DPPADD_(v, 0x118, 0xf);  // row_shr:8
  v = DPPADD_(v, 0x142, 0xa);  // row_bcast:15 -> rows 1,3
  v = DPPADD_(v, 0x143, 0xc);  // row_bcast:31 -> rows 2,3
  return v;
}

// ua layout: float2 {u, A} per (position, channel):
//   ua[blk*16384 + pos_in_chunk*256 + 2*ch + {0,1}]

// ---------------- layer 0 prep + chunk totals (+ weight convert tail) -------
// blocks [0,2048): one chunk each; 256 thr = 4 waves; wave = one position/iter.
// blocks [2048,2176): convert [Wz;Wh] of layers 1,2 to bf16 256x128.
__global__ __launch_bounds__(256) void prep0c_kernel(
    const float* __restrict__ x,
    const float* __restrict__ Wz, const float* __restrict__ bz,
    const float* __restrict__ Wh, const float* __restrict__ bh,
    float* __restrict__ ua, float* __restrict__ tot,
    const float* __restrict__ Wz1, const float* __restrict__ Wh1,
    const float* __restrict__ Wz2, const float* __restrict__ Wh2,
    unsigned short* __restrict__ Wc1, unsigned short* __restrict__ Wc2)
{
  __shared__ float tpart[4][128];
  if (blockIdx.x >= 2048) {            // weight-convert tail blocks
    int idx = (blockIdx.x - 2048) * 256 + threadIdx.x;  // < 32768
    Wc1[idx] = f2bf_(idx < 16384 ? Wz1[idx] : Wh1[idx - 16384]);
    Wc2[idx] = f2bf_(idx < 16384 ? Wz2[idx] : Wh2[idx - 16384]);
    return;
  }
  int lane = threadIdx.x & 63, w = threadIdx.x >> 6;
  float wz0 = Wz[lane], wz1 = Wz[lane + 64];
  float bz0 = bz[lane], bz1 = bz[lane + 64];
  float wh0 = Wh[lane], wh1 = Wh[lane + 64];
  float bh0 = bh[lane], bh1 = bh[lane + 64];
  int blk = blockIdx.x;                       // b*NC + c
  size_t base2 = (size_t)blk * (CH_ * 256);
  int pos0 = blk * CH_;
  float xv[16];
  #pragma unroll
  for (int j = 0; j < 16; ++j) xv[j] = x[pos0 + j * 4 + w];
  float t0 = NEGINF_, t1 = NEGINF_;
  #pragma unroll
  for (int j = 0; j < 16; ++j) {
    int i = j * 4 + w;
    float k0 = fmaf(xv[j], wz0, bz0), k1 = fmaf(xv[j], wz1, bz1);
    float g0 = fmaf(xv[j], wh0, bh0), g1 = fmaf(xv[j], wh1, bh1);
    float lc0 = -sp_(k0), lc1 = -sp_(k1);
    float lv0 = k0 + lc0 + logg_(g0);   // -sp(-k) == k - sp(k)
    float lv1 = k1 + lc1 + logg_(g1);
    float s0 = wscan_(lc0);
    float c0 = __shfl(s0, 63, 64);
    float s1 = wscan_(lc1) + c0;
    float u0 = lv0 - s0, u1 = lv1 - s1;
    size_t o2 = base2 + (size_t)i * 256;
    *reinterpret_cast<float2*>(&ua[o2 + 2 * lane])       = make_float2(u0, s0);
    *reinterpret_cast<float2*>(&ua[o2 + 128 + 2 * lane]) = make_float2(u1, s1);
    t0 = lae_(t0, u0); t1 = lae_(t1, u1);
  }
  tpart[w][lane] = t0; tpart[w][64 + lane] = t1;
  __syncthreads();
  if (w == 0) {
    int ch = lane;
    tot[(size_t)blk * H_ + ch] =
        lae_(lae_(tpart[0][ch], tpart[1][ch]), lae_(tpart[2][ch], tpart[3][ch]));
    ch = lane + 64;
    tot[(size_t)blk * H_ + ch] =
        lae_(lae_(tpart[0][ch], tpart[1][ch]), lae_(tpart[2][ch], tpart[3][ch]));
  }
}

// ---------------- fused: carry + scan3(layer l) + matmul xW(l+1) + epilogue -
// block = one chunk; 256 thr = 4 waves. h stays in LDS (bf16). ua in-place.
__global__ __launch_bounds__(256) void kb_kernel(
    const float* __restrict__ totIn,          // layer l chunk totals
    const unsigned short* __restrict__ Wc,    // layer l+1 [256][128] bf16
    const float* __restrict__ bz, const float* __restrict__ bh,
    float* __restrict__ ua,                   // in: layer l, out: layer l+1
    float* __restrict__ totOut)               // out: layer l+1 chunk totals
{
  __shared__ unsigned short hT[64][HTP_]; // 17.0 KB h of layer l (bf16), padded
  __shared__ union {
    float kg[16][260];                    // 16.25 KB one 16-row m-tile of [k|g]
    float scr[32][128];                   // 16 KB half1 local scans (phase 1)
  } ks;
  __shared__ float thand[128];            // half0 -> half1 carry handoff
  __shared__ float tpart[4][128];         // carry partials / per-wave tot partials
  int tid = threadIdx.x;
  int lane = tid & 63, w = tid >> 6;
  int l15 = lane & 15, quad = lane >> 4;
  int half = tid >> 7, ch = tid & 127;
  int blk = blockIdx.x;
  int cidx = blk & (NC_ - 1);             // chunk index within its chain
  size_t base2 = (size_t)blk * (CH_ * 256);

  // ---- carry preamble: reduce tot[chain, 0..cidx-1, ch] ----
  {
    const float* tp = totIn + (size_t)(blk - cidx) * H_ + ch;
    float p0 = NEGINF_, p1 = NEGINF_;
    int i = half;
    for (; i + 2 < cidx; i += 4) {
      float a0 = tp[(size_t)i * H_];
      float a1 = tp[(size_t)(i + 2) * H_];
      p0 = lae_(p0, a0); p1 = lae_(p1, a1);
    }
    for (; i < cidx; i += 2) p0 = lae_(p0, tp[(size_t)i * H_]);
    tpart[half * 2][ch] = p0; tpart[half * 2 + 1][ch] = p1;
  }
  __syncthreads();

  const float* stp = ua + base2 + 2 * ch;

  // ---- phase 1a ----
  if (half == 0) {
    float r = LOGHALF_;                     // t=0 init, then fold carry partials
    r = lae_(r, tpart[0][ch]); r = lae_(r, tpart[1][ch]);
    r = lae_(r, tpart[2][ch]); r = lae_(r, tpart[3][ch]);
    float uv[32], av[32];
    #pragma unroll
    for (int i = 0; i < 32; ++i) {
      float2 v = *reinterpret_cast<const float2*>(stp + (size_t)i * 256);
      uv[i] = v.x; av[i] = v.y;
    }
    #pragma unroll
    for (int i = 0; i < 32; ++i) {
      r = lae_(r, uv[i]);
      hT[i][ch] = f2bf_(sigm_(__expf(av[i] + r)));
    }
    thand[ch] = r;   // carry into position 32
  } else {
    float r = NEGINF_;
    float uv[32];
    #pragma unroll
    for (int i = 0; i < 32; ++i)
      uv[i] = stp[(size_t)(32 + i) * 256];
    #pragma unroll
    for (int i = 0; i < 32; ++i) { r = lae_(r, uv[i]); ks.scr[i][ch] = r; }
  }
  __syncthreads();
  // ---- phase 1b: half1 fixup with half0's carry ----
  if (half == 1) {
    float r31 = thand[ch];
    float av[32];
    #pragma unroll
    for (int i = 0; i < 32; ++i) av[i] = stp[(size_t)(32 + i) * 256 + 1];
    #pragma unroll
    for (int i = 0; i < 32; ++i) {
      float ri = lae_(r31, ks.scr[i][ch]);
      hT[32 + i][ch] = f2bf_(sigm_(__expf(av[i] + ri)));
    }
  }
  __syncthreads();

  float bz0v = bz[lane], bz1v = bz[lane + 64];
  float bh0v = bh[lane], bh1v = bh[lane + 64];
  float t0 = NEGINF_, t1 = NEGINF_;

  // ---- phase 2/3 per 16-row m-tile: MFMA then epilogue ----
  // wave w owns output cols [64w, 64w+64) of N=256 ([k|g]).
  for (int t = 0; t < 4; ++t) {
    f32x4 z = {0.f, 0.f, 0.f, 0.f};
    f32x4 acc[4] = {z, z, z, z};
    #pragma unroll
    for (int kk = 0; kk < 4; ++kk) {
      bf16x8 a = *reinterpret_cast<const bf16x8*>(&hT[t * 16 + l15][kk * 32 + quad * 8]);
      #pragma unroll
      for (int nt = 0; nt < 4; ++nt) {
        int n = w * 64 + nt * 16 + l15;
        bf16x8 bf = *reinterpret_cast<const bf16x8*>(Wc + n * 128 + kk * 32 + quad * 8);
        acc[nt] = __builtin_amdgcn_mfma_f32_16x16x32_bf16(a, bf, acc[nt], 0, 0, 0);
      }
    }
    __syncthreads();  // previous epilogue done reading kg (tile 0: scr dead)
    #pragma unroll
    for (int nt = 0; nt < 4; ++nt) {
      int col = w * 64 + nt * 16 + l15;
      #pragma unroll
      for (int r2 = 0; r2 < 4; ++r2)
        ks.kg[quad * 4 + r2][col] = acc[nt][r2];   // D: row=quad*4+r2, col=l15
    }
    __syncthreads();
    #pragma unroll
    for (int i = 0; i < 4; ++i) {
      int row = w + i * 4;            // wave-interleaved rows of the m-tile
      int sIdx = t * 16 + row;
      float k0 = ks.kg[row][lane]        + bz0v;
      float k1 = ks.kg[row][64 + lane]   + bz1v;
      float g0 = ks.kg[row][128 + lane]  + bh0v;
      float g1 = ks.kg[row][192 + lane]  + bh1v;
      float lc0 = -sp_(k0), lc1 = -sp_(k1);
      float lv0 = k0 + lc0 + logg_(g0);
      float lv1 = k1 + lc1 + logg_(g1);
      float s0 = wscan_(lc0);
      float c0 = __shfl(s0, 63, 64);
      float s1 = wscan_(lc1) + c0;
      float u0 = lv0 - s0, u1 = lv1 - s1;
      size_t o2 = base2 + (size_t)sIdx * 256;
      *reinterpret_cast<float2*>(&ua[o2 + 2 * lane])       = make_float2(u0, s0);
      *reinterpret_cast<float2*>(&ua[o2 + 128 + 2 * lane]) = make_float2(u1, s1);
      t0 = lae_(t0, u0); t1 = lae_(t1, u1);
    }
  }

  // ---- combine chunk totals across the 4 waves ----
  tpart[w][lane] = t0; tpart[w][64 + lane] = t1;
  __syncthreads();
  if (w == 0) {
    int c = lane;
    totOut[(size_t)blk * H_ + c] =
        lae_(lae_(tpart[0][c], tpart[1][c]), lae_(tpart[2][c], tpart[3][c]));
    c = lane + 64;
    totOut[(size_t)blk * H_ + c] =
        lae_(lae_(tpart[0][c], tpart[1][c]), lae_(tpart[2][c], tpart[3][c]));
  }
}

// ---------------- layer 2 final scan -> hbf (bf16), split-chain + carry -----
__global__ __launch_bounds__(256) void scan3v2_kernel(
    const float* __restrict__ ua,
    const float* __restrict__ totIn, unsigned short* __restrict__ hbf)
{
  __shared__ float scr[32][128];
  __shared__ float thand[128];
  __shared__ float tpart[4][128];
  int tid = threadIdx.x;
  int half = tid >> 7, ch = tid & 127;
  int blk = blockIdx.x;
  int cidx = blk & (NC_ - 1);
  size_t base2 = (size_t)blk * (CH_ * 256);
  size_t baseh = (size_t)blk * (CH_ * H_);
  const float* stp = ua + base2 + 2 * ch;
  unsigned short* hp = hbf + baseh + ch;

  // ---- carry preamble ----
  {
    const float* tp = totIn + (size_t)(blk - cidx) * H_ + ch;
    float p0 = NEGINF_, p1 = NEGINF_;
    int i = half;
    for (; i + 2 < cidx; i += 4) {
      float a0 = tp[(size_t)i * H_];
      float a1 = tp[(size_t)(i + 2) * H_];
      p0 = lae_(p0, a0); p1 = lae_(p1, a1);
    }
    for (; i < cidx; i += 2) p0 = lae_(p0, tp[(size_t)i * H_]);
    tpart[half * 2][ch] = p0; tpart[half * 2 + 1][ch] = p1;
  }
  __syncthreads();

  if (half == 0) {
    float r = LOGHALF_;
    r = lae_(r, tpart[0][ch]); r = lae_(r, tpart[1][ch]);
    r = lae_(r, tpart[2][ch]); r = lae_(r, tpart[3][ch]);
    float uv[32], av[32];
    #pragma unroll
    for (int i = 0; i < 32; ++i) {
      float2 v = *reinterpret_cast<const float2*>(stp + (size_t)i * 256);
      uv[i] = v.x; av[i] = v.y;
    }
    #pragma unroll
    for (int i = 0; i < 32; ++i) {
      r = lae_(r, uv[i]);
      hp[(size_t)i * H_] = f2bf_(sigm_(__expf(av[i] + r)));
    }
    thand[ch] = r;
  } else {
    float r = NEGINF_;
    float uv[32];
    #pragma unroll
    for (int i = 0; i < 32; ++i) uv[i] = stp[(size_t)(32 + i) * 256];
    #pragma unroll
    for (int i = 0; i < 32; ++i) { r = lae_(r, uv[i]); scr[i][ch] = r; }
  }
  __syncthreads();
  if (half == 1) {
    float r31 = thand[ch];
    float av[32];
    #pragma unroll
    for (int i = 0; i < 32; ++i) av[i] = stp[(size_t)(32 + i) * 256 + 1];
    #pragma unroll
    for (int i = 0; i < 32; ++i) {
      float ri = lae_(r31, scr[i][ch]);
      hp[(size_t)(32 + i) * H_] = f2bf_(sigm_(__expf(av[i] + ri)));
    }
  }
}

// ---------------- final matmul: out[32,128] = h2flat @ Wout^T + bout --------
// 2-stage register pipeline; NKS=512 (2048 regressed twice).
__device__ __forceinline__ void omload_(
    const unsigned short* ap0, const unsigned short* ap1,
    const float* wp0, const float* wp1, int k,
    bf16x8& a0r, bf16x8& a1r, float4 (&wr)[2][2])
{
  a0r = *reinterpret_cast<const bf16x8*>(ap0 + k);
  a1r = *reinterpret_cast<const bf16x8*>(ap1 + k);
  wr[0][0] = *reinterpret_cast<const float4*>(wp0 + k);
  wr[0][1] = *reinterpret_cast<const float4*>(wp0 + k + 4);
  wr[1][0] = *reinterpret_cast<const float4*>(wp1 + k);
  wr[1][1] = *reinterpret_cast<const float4*>(wp1 + k + 4);
}
__device__ __forceinline__ void omstep_(
    const bf16x8& a0r, const bf16x8& a1r,
    const float4 (&wr)[2][2], f32x4 (&acc)[2][2])
{
  #pragma unroll
  for (int nt = 0; nt < 2; ++nt) {
    ushort8_t tt;
    tt[0] = f2bf_(wr[nt][0].x); tt[1] = f2bf_(wr[nt][0].y);
    tt[2] = f2bf_(wr[nt][0].z); tt[3] = f2bf_(wr[nt][0].w);
    tt[4] = f2bf_(wr[nt][1].x); tt[5] = f2bf_(wr[nt][1].y);
    tt[6] = f2bf_(wr[nt][1].z); tt[7] = f2bf_(wr[nt][1].w);
    bf16x8 bf = __builtin_bit_cast(bf16x8, tt);
    acc[0][nt] = __builtin_amdgcn_mfma_f32_16x16x32_bf16(a0r, bf, acc[0][nt], 0, 0, 0);
    acc[1][nt] = __builtin_amdgcn_mfma_f32_16x16x32_bf16(a1r, bf, acc[1][nt], 0, 0, 0);
  }
}

__global__ __launch_bounds__(256) void outmm_kernel(
    const unsigned short* __restrict__ hbf,  // 32 x 524288 bf16
    const float* __restrict__ Wout,          // 128 x 524288 fp32
    float* __restrict__ part)
{
  const int KSL = KTOT_ / NKS_;  // 1024
  int tid = threadIdx.x, w = tid >> 6, lane = tid & 63;
  int l15 = lane & 15, quad = lane >> 4;
  int k0base = blockIdx.x * KSL;
  const unsigned short* ap0 = hbf + (size_t)l15 * KTOT_ + k0base + quad * 8;
  const unsigned short* ap1 = hbf + (size_t)(16 + l15) * KTOT_ + k0base + quad * 8;
  const float* wp0 = Wout + (size_t)(w * 32 + l15) * KTOT_ + k0base + quad * 8;
  const float* wp1 = Wout + (size_t)(w * 32 + 16 + l15) * KTOT_ + k0base + quad * 8;
  f32x4 acc[2][2] = {{{0,0,0,0},{0,0,0,0}},{{0,0,0,0},{0,0,0,0}}};
  bf16x8 aA0, aA1, aB0, aB1;
  float4 wvA[2][2], wvB[2][2];
  omload_(ap0, ap1, wp0, wp1, 0, aA0, aA1, wvA);
  for (int ks = 0; ks < KSL; ks += 64) {
    omload_(ap0, ap1, wp0, wp1, ks + 32, aB0, aB1, wvB);
    omstep_(aA0, aA1, wvA, acc);
    if (ks + 64 < KSL) omload_(ap0, ap1, wp0, wp1, ks + 64, aA0, aA1, wvA);
    omstep_(aB0, aB1, wvB, acc);
  }
  float* pp = part + (size_t)blockIdx.x * (B_ * OUT_);
  #pragma unroll
  for (int mt = 0; mt < 2; ++mt)
    #pragma unroll
    for (int nt = 0; nt < 2; ++nt)
      #pragma unroll
      for (int r = 0; r < 4; ++r) {
        int b = mt * 16 + quad * 4 + r;
        int o = w * 32 + nt * 16 + l15;
        pp[b * OUT_ + o] = acc[mt][nt][r];
      }
}

// ---------------- coalesced split-K reduction ------------------------------
// 64 blocks x 64 outputs. Lane reads part[wg][idx0+lane]: contiguous 256B per
// wave-instruction.
__global__ __launch_bounds__(256) void outred_kernel(
    const float* __restrict__ part, const float* __restrict__ bout,
    float* __restrict__ out)
{
  __shared__ float red[4][64];
  int w = threadIdx.x >> 6, lane = threadIdx.x & 63;
  int idx0 = blockIdx.x * 64;
  float s = 0.f;
  for (int wg = w; wg < NKS_; wg += 4)
    s += part[(size_t)wg * (B_ * OUT_) + idx0 + lane];
  red[w][lane] = s;
  __syncthreads();
  if (w == 0) {
    float r = (red[0][lane] + red[1][lane]) + (red[2][lane] + red[3][lane]);
    int idx = idx0 + lane;
    out[idx] = r + bout[idx & (OUT_ - 1)];
  }
}

// ---------------- host launcher ----------------
extern "C" void kernel_launch(void* const* d_in, const int* in_sizes, int n_in,
                              void* d_out, int out_size, void* d_ws, size_t ws_size,
                              hipStream_t stream)
{
  const float* x    = (const float*)d_in[0];
  const float* Wz[3] = {(const float*)d_in[1], (const float*)d_in[5], (const float*)d_in[9]};
  const float* bz[3] = {(const float*)d_in[2], (const float*)d_in[6], (const float*)d_in[10]};
  const float* Wh[3] = {(const float*)d_in[3], (const float*)d_in[7], (const float*)d_in[11]};
  const float* bh[3] = {(const float*)d_in[4], (const float*)d_in[8], (const float*)d_in[12]};
  const float* Wout = (const float*)d_in[13];
  const float* bout = (const float*)d_in[14];
  float* out = (float*)d_out;

  char* ws = (char*)d_ws;
  float*          ua    = (float*)(ws + 0);                  // 128 MiB {u,A}
  unsigned short* hbf   = (unsigned short*)(ws + 134217728); // 32 MiB
  unsigned short* Wc1   = (unsigned short*)(ws + 167772160); // 64 KiB
  unsigned short* Wc2   = (unsigned short*)(ws + 167837696); // 64 KiB
  float*          totA  = (float*)(ws + 167903232);          // 1 MiB
  float*          totB  = (float*)(ws + 168951808);          // 1 MiB
  float*          part  = (float*)(ws + 170000384);          // 8 MiB

  // layer 0 prep + totals (+ weight convert in tail blocks)
  prep0c_kernel<<<B_ * NC_ + 128, 256, 0, stream>>>(
      x, Wz[0], bz[0], Wh[0], bh[0], ua, totA,
      Wz[1], Wh[1], Wz[2], Wh[2], Wc1, Wc2);

  // layer 0 -> 1 fused, layer 1 -> 2 fused (tot ping-pongs A->B->A)
  kb_kernel<<<B_ * NC_, 256, 0, stream>>>(totA, Wc1, bz[1], bh[1], ua, totB);
  kb_kernel<<<B_ * NC_, 256, 0, stream>>>(totB, Wc2, bz[2], bh[2], ua, totA);

  // layer 2 final scan -> hbf
  scan3v2_kernel<<<B_ * NC_, 256, 0, stream>>>(ua, totA, hbf);

  // output head
  outmm_kernel<<<NKS_, 256, 0, stream>>>(hbf, Wout, part);
  outred_kernel<<<(B_ * OUT_) / 64, 256, 0, stream>>>(part, bout, out);
}